// Round 8
// baseline (1742.970 us; speedup 1.0000x reference)
//
#include <hip/hip_runtime.h>

#define N_E 8192
#define E_DIM 512
#define NROWS 32768          // 16*2048
#define TOT_ELEMS 16777216   // 16*2048*512
#define BETA 0.25f

// ---- MFMA argmin GEMM geometry ----
#define GBM 128              // rows per block
#define GBN 256              // cols per block (4 waves x 64)
#define GBK 64               // k per tile (8 tiles cover K=512)
#define NGROUPS 128          // 8192 / 64-col groups
#define MARGIN 3.0e-4f       // >= 2*eps(bf16 approx); R7-validated (absmax 0.0)

typedef __attribute__((ext_vector_type(8))) short short8v;   // 8 bf16 (4 VGPR)
typedef __attribute__((ext_vector_type(4))) float f32x4;     // MFMA C/D

__device__ __forceinline__ unsigned short f2bf(float f) {    // RTNE fp32->bf16
    unsigned u = __float_as_uint(f);
    u += 0x7FFFu + ((u >> 16) & 1u);
    return (unsigned short)(u >> 16);
}

// ---------------- Kernel 1: row norms ||z_r||^2 (fp64 acc) + z -> bf16 conversion -----
// Fused: z is read once; writes z2 (f32) and zb (bf16, RTNE) for the MFMA stage.
__global__ __launch_bounds__(256) void z2_kernel(const float* __restrict__ z,
                                                 float* __restrict__ z2,
                                                 unsigned long long* __restrict__ zb8) {
    int row  = blockIdx.x * 4 + (threadIdx.x >> 6);
    int lane = threadIdx.x & 63;
    const float4* p = (const float4*)(z + (size_t)row * E_DIM);
    double s = 0.0;
#pragma unroll
    for (int it = 0; it < 2; ++it) {
        float4 v = p[lane + it * 64];
        s += (double)v.x * v.x + (double)v.y * v.y
           + (double)v.z * v.z + (double)v.w * v.w;
        unsigned long long pk =
              (unsigned long long)((unsigned)f2bf(v.x) | ((unsigned)f2bf(v.y) << 16))
            | ((unsigned long long)((unsigned)f2bf(v.z) | ((unsigned)f2bf(v.w) << 16)) << 32);
        zb8[(size_t)row * 128 + lane + it * 64] = pk;
    }
#pragma unroll
    for (int off = 32; off > 0; off >>= 1) s += __shfl_down(s, off);
    if (lane == 0) z2[row] = (float)s;
}

// ---------------- Kernel 1b: emb fp32 -> bf16 (RTNE), packed u64 stores ---------------
__global__ __launch_bounds__(256) void convb_kernel(const float* __restrict__ emb,
                                                    unsigned long long* __restrict__ embb8) {
    int t = blockIdx.x * 256 + threadIdx.x;     // 1,048,576 threads x 4 elems
    float4 v = ((const float4*)emb)[t];
    unsigned long long p =
          (unsigned long long)((unsigned)f2bf(v.x) | ((unsigned)f2bf(v.y) << 16))
        | ((unsigned long long)((unsigned)f2bf(v.z) | ((unsigned)f2bf(v.w) << 16)) << 32);
    embb8[t] = p;
}

// ---------------- Kernel 2: bf16 MFMA approx scores + per-64-col-group min VALUE ------
// Approx w(r,n) = z2_r - 2*(bf16 z . bf16 e), fp32 MFMA accumulate. Only the per-group
// MIN VALUE is needed: rescore fully (exactly) rescans every group within MARGIN of the
// global approx min, which is guaranteed to include the true winner's group
// (m1[g*] <= approx(c*) <= exact_min + eps <= approx_gm + 2*eps <= thr).
// vs R7: A staged as pre-converted bf16 (no in-loop f2bf -> ~96 VALU-cyc/tile/wave
// saved, and A-fetch bytes halve), fold is value-only (no u64 packing / dual reduce).
__global__ __launch_bounds__(512) void gemm_argmin_kernel(
        const unsigned short* __restrict__ zb,
        const unsigned short* __restrict__ embb,
        const float* __restrict__ z2s,
        float* __restrict__ m1g) {
    __shared__ __align__(16) unsigned short Al[GBM * GBK];   // 16 KB swizzled
    __shared__ __align__(16) unsigned short Bl[GBN * GBK];   // 32 KB swizzled
    __shared__ float z2sh[GBM];

    const int tid  = threadIdx.x;
    const int lane = tid & 63;
    const int wid  = tid >> 6;
    const int wr   = wid >> 2;          // 0..1 row half
    const int wc   = wid & 3;           // 0..3 col quarter
    const int bx   = blockIdx.x & 31;   // 32 n-blocks
    const int by   = blockIdx.x >> 5;   // 256 row-blocks
    const int row0 = by * GBM;
    const int nb0  = bx * GBN;

    if (tid < GBM) z2sh[tid] = z2s[row0 + tid];

    // ---- staging geometry: 16B granules; A: 1024 granules (2/thread), B: 2048 (4/thread)
    const int cA   = tid * 2;
    const int rowA = cA >> 3;                    // 0..127
    const int grA  = cA & 7;                     // 0,2,4,6
    const unsigned short* gA = zb + (size_t)(row0 + rowA) * E_DIM + grA * 8;
    const int swA0 = rowA * 128 + (((grA    ) ^ (rowA & 7)) << 4);
    const int swA1 = rowA * 128 + (((grA + 1) ^ (rowA & 7)) << 4);

    const int cB   = tid * 4;
    const int rowB = cB >> 3;                    // 0..255
    const int grB  = cB & 7;                     // 0 or 4
    const unsigned short* gB = embb + (size_t)(nb0 + rowB) * E_DIM + grB * 8;
    const int swB0 = rowB * 128 + (((grB    ) ^ (rowB & 7)) << 4);
    const int swB1 = rowB * 128 + (((grB + 1) ^ (rowB & 7)) << 4);
    const int swB2 = rowB * 128 + (((grB + 2) ^ (rowB & 7)) << 4);
    const int swB3 = rowB * 128 + (((grB + 3) ^ (rowB & 7)) << 4);

    // ---- fragment read byte-offsets for kh=0; kh=1 is ^64 (granule+4 under the XOR)
    int aoff[4], boff[4];
#pragma unroll
    for (int ri = 0; ri < 4; ++ri) {
        int rowf = wr * 64 + ri * 16 + (lane & 15);
        aoff[ri] = rowf * 128 + (((lane >> 4) ^ (rowf & 7)) << 4);
    }
#pragma unroll
    for (int ci = 0; ci < 4; ++ci) {
        int rowf = wc * 64 + ci * 16 + (lane & 15);
        boff[ci] = rowf * 128 + (((lane >> 4) ^ (rowf & 7)) << 4);
    }

    f32x4 acc[4][4];
#pragma unroll
    for (int a = 0; a < 4; ++a)
#pragma unroll
        for (int b = 0; b < 4; ++b) acc[a][b] = (f32x4){0.f, 0.f, 0.f, 0.f};

    // ---- prologue: register-prefetch k-tile 0 (R1-proven two-barrier structure)
    short8v pa0 = *(const short8v*)(gA + 0);
    short8v pa1 = *(const short8v*)(gA + 8);
    short8v pb0 = *(const short8v*)(gB + 0);
    short8v pb1 = *(const short8v*)(gB + 8);
    short8v pb2 = *(const short8v*)(gB + 16);
    short8v pb3 = *(const short8v*)(gB + 24);

    for (int kt = 0; kt < 8; ++kt) {
        // write staged regs -> LDS
        *(short8v*)((char*)Al + swA0) = pa0;
        *(short8v*)((char*)Al + swA1) = pa1;
        *(short8v*)((char*)Bl + swB0) = pb0;
        *(short8v*)((char*)Bl + swB1) = pb1;
        *(short8v*)((char*)Bl + swB2) = pb2;
        *(short8v*)((char*)Bl + swB3) = pb3;
        __syncthreads();

        // issue next tile's global loads (hidden behind this tile's MFMA)
        if (kt < 7) {
            const unsigned short* za = gA + (kt + 1) * GBK;
            pa0 = *(const short8v*)(za + 0);
            pa1 = *(const short8v*)(za + 8);
            const unsigned short* eb = gB + (kt + 1) * GBK;
            pb0 = *(const short8v*)(eb + 0);
            pb1 = *(const short8v*)(eb + 8);
            pb2 = *(const short8v*)(eb + 16);
            pb3 = *(const short8v*)(eb + 24);
        }

        // compute: 2 k-halves x 4x4 fragments = 32 MFMA
#pragma unroll
        for (int kh = 0; kh < 2; ++kh) {
            short8v af[4], bfr[4];
#pragma unroll
            for (int ri = 0; ri < 4; ++ri)
                af[ri] = *(const short8v*)((const char*)Al + (aoff[ri] ^ (kh << 6)));
#pragma unroll
            for (int ci = 0; ci < 4; ++ci)
                bfr[ci] = *(const short8v*)((const char*)Bl + (boff[ci] ^ (kh << 6)));
#pragma unroll
            for (int ri = 0; ri < 4; ++ri)
#pragma unroll
                for (int ci = 0; ci < 4; ++ci)
                    acc[ri][ci] = __builtin_amdgcn_mfma_f32_16x16x32_bf16(
                        af[ri], bfr[ci], acc[ri][ci], 0, 0, 0);
        }
        __syncthreads();
    }

    // ---- fold: per row, min VALUE over this wave's 64 cols -> group table
    const int gidx = bx * 4 + wc;                 // 64-col group id, 0..127
#pragma unroll
    for (int ri = 0; ri < 4; ++ri) {
#pragma unroll
        for (int i = 0; i < 4; ++i) {
            int row = wr * 64 + ri * 16 + ((lane >> 4) << 2) + i;
            float z2r = z2sh[row];
            float w = fminf(fminf(z2r - 2.f * acc[ri][0][i],
                                  z2r - 2.f * acc[ri][1][i]),
                            fminf(z2r - 2.f * acc[ri][2][i],
                                  z2r - 2.f * acc[ri][3][i]));
            // reduce over the 16 lanes sharing this row (lane bits 4-5 unchanged)
#pragma unroll
            for (int off = 1; off < 16; off <<= 1)
                w = fminf(w, __shfl_xor(w, off));
            if ((lane & 15) == 0)
                m1g[(size_t)(row0 + row) * NGROUPS + gidx] = w;
        }
    }
}

// ---------------- Kernel 3: exact rescore of margin groups ---------------------------
// Reproduces the reference comparison EXACTLY: serial fp32 fma chain k=0..511 ascending,
// w = z2 - 2*acc (single rounding), ties -> lowest index. Every group whose approx min
// is within MARGIN of the global approx min is fully rescanned (64 cols, one per lane).
__device__ __forceinline__ float exact_w(const float* zs, const float* __restrict__ emb,
                                         int col, float z2r) {
    const float* e = emb + (size_t)col * E_DIM;
    float acc = 0.f;
#pragma unroll 8
    for (int k = 0; k < E_DIM; ++k) acc = fmaf(zs[k], e[k], acc);
    return z2r - 2.f * acc;
}

__global__ __launch_bounds__(256) void rescore_kernel(
        const float* __restrict__ z, const float* __restrict__ emb,
        const float* __restrict__ z2s,
        const float* __restrict__ m1g,
        float* __restrict__ idxf) {
    __shared__ __align__(16) float zsh[4][512];
    const int lane = threadIdx.x & 63;
    const int wid  = threadIdx.x >> 6;
    const int r    = blockIdx.x * 4 + wid;

    const float4* zr4 = (const float4*)(z + (size_t)r * E_DIM);
    ((float4*)zsh[wid])[lane]      = zr4[lane];
    ((float4*)zsh[wid])[lane + 64] = zr4[lane + 64];
    __syncthreads();
    const float* zs  = zsh[wid];
    const float  z2r = z2s[r];

    float a = m1g[(size_t)r * NGROUPS + lane];
    float b = m1g[(size_t)r * NGROUPS + 64 + lane];

    float gm = fminf(a, b);
#pragma unroll
    for (int off = 1; off < 64; off <<= 1)
        gm = fminf(gm, __shfl_xor(gm, off));
    const float thr = gm + MARGIN;

    float wb = 3.4e38f; int ib = 0x7fffffff;
    unsigned long long mfa = __ballot(a <= thr);
    unsigned long long mfb = __ballot(b <= thr);
    while (mfa) {
        int g = __ffsll((long long)mfa) - 1; mfa &= mfa - 1;
        int col = g * 64 + lane;
        float w = exact_w(zs, emb, col, z2r);
        if (w < wb || (w == wb && col < ib)) { wb = w; ib = col; }
    }
    while (mfb) {
        int g = __ffsll((long long)mfb) - 1; mfb &= mfb - 1;
        int col = (64 + g) * 64 + lane;
        float w = exact_w(zs, emb, col, z2r);
        if (w < wb || (w == wb && col < ib)) { wb = w; ib = col; }
    }
#pragma unroll
    for (int off = 1; off < 64; off <<= 1) {
        float wo = __shfl_xor(wb, off);
        int  io  = __shfl_xor(ib, off);
        if (wo < wb || (wo == wb && io < ib)) { wb = wo; ib = io; }
    }
    if (lane == 0) idxf[r] = (float)ib;
}

// ---------------- Kernel 4: gather + straight-through output + loss ----------------
__global__ __launch_bounds__(256) void output_kernel(const float* __restrict__ z,
                                                     const float* __restrict__ mask,
                                                     const float* __restrict__ emb,
                                                     const float* __restrict__ idxf,
                                                     float* __restrict__ out0,
                                                     float* __restrict__ loss) {
    const int nth = gridDim.x * blockDim.x;
    int t = blockIdx.x * blockDim.x + threadIdx.x;
    const float4* z4 = (const float4*)z;
    const float4* e4 = (const float4*)emb;
    float4* o4 = (float4*)out0;
    float partial = 0.f;
    for (int f = t; f < TOT_ELEMS / 4; f += nth) {
        int row = f >> 7;            // 128 float4 per 512-elem row
        int col = f & 127;
        int id  = (int)idxf[row];
        float m = mask[row];
        float4 zv = z4[f];
        float4 qv = e4[id * 128 + col];
        float dx = qv.x - zv.x, dy = qv.y - zv.y;
        float dz = qv.z - zv.z, dw = qv.w - zv.w;
        float4 ov;                   // z + (z_q - z): fp32 replication of ST estimator
        ov.x = zv.x + dx; ov.y = zv.y + dy;
        ov.z = zv.z + dz; ov.w = zv.w + dw;
        o4[f] = ov;
        partial += (dx * dx + dy * dy + dz * dz + dw * dw) * m;
    }
#pragma unroll
    for (int off = 32; off > 0; off >>= 1) partial += __shfl_down(partial, off);
    __shared__ float wsum[4];
    int lane = threadIdx.x & 63, w = threadIdx.x >> 6;
    if (lane == 0) wsum[w] = partial;
    __syncthreads();
    if (threadIdx.x == 0) {
        float s = wsum[0] + wsum[1] + wsum[2] + wsum[3];
        atomicAdd(loss, s * ((1.f + BETA) / (float)TOT_ELEMS));
    }
}

// ---------------- launcher -----------------------------------------------------------
// Scratch layout inside out0 (overwritten by output_kernel at the very end):
//   [0          .. 16,777,216)  m1g   f32[32768][128]   (group approx mins)
//   [16,777,216 .. 50,331,648)  zb    bf16[32768][512]
//   [50,331,648 .. 58,720,256)  embb  bf16[8192][512]
//   [58,720,256 .. 58,851,328)  z2    f32[32768]
extern "C" void kernel_launch(void* const* d_in, const int* in_sizes, int n_in,
                              void* d_out, int out_size, void* d_ws, size_t ws_size,
                              hipStream_t stream) {
    const float* z    = (const float*)d_in[0];   // (16,2048,512)
    const float* mask = (const float*)d_in[1];   // (16,2048)
    const float* emb  = (const float*)d_in[2];   // (8192,512)

    float* out0 = (float*)d_out;                 // z_q_st: 16777216 floats
    float* out1 = out0 + TOT_ELEMS;              // idx as float: 32768
    float* loss = out1 + NROWS;                  // scalar

    char* base = (char*)d_out;
    float*          m1g  = (float*)base;
    unsigned short* zb   = (unsigned short*)(base + 16777216);
    unsigned short* embb = (unsigned short*)(base + 50331648);
    float*          z2st = (float*)(base + 58720256);

    hipMemsetAsync(loss, 0, sizeof(float), stream);
    z2_kernel<<<NROWS / 4, 256, 0, stream>>>(z, z2st, (unsigned long long*)zb);
    convb_kernel<<<4096, 256, 0, stream>>>(emb, (unsigned long long*)embb);
    gemm_argmin_kernel<<<(NROWS / GBM) * (N_E / GBN), 512, 0, stream>>>(
        zb, embb, z2st, m1g);
    rescore_kernel<<<NROWS / 4, 256, 0, stream>>>(z, emb, z2st, m1g, out1);
    output_kernel<<<4096, 256, 0, stream>>>(z, mask, emb, out1, out0, loss);
}

// Round 9
// 884.595 us; speedup vs baseline: 1.9704x; 1.9704x over previous
//
#include <hip/hip_runtime.h>

#define N_E 8192
#define E_DIM 512
#define NROWS 32768          // 16*2048
#define TOT_ELEMS 16777216   // 16*2048*512
#define BETA 0.25f

// ---- MFMA argmin GEMM geometry ----
#define GBM 128              // rows per block
#define GBN 256              // cols per block (4 waves x 64)
#define GBK 64               // k per tile (8 tiles cover K=512)
#define NGROUPS 64           // 8192 / 128-col groups
#define MARGIN 3.0e-4f       // >= 2*eps(bf16 approx); R7-validated (absmax 0.0)

typedef __attribute__((ext_vector_type(8))) short short8v;   // 8 bf16 (4 VGPR)
typedef __attribute__((ext_vector_type(4))) float f32x4;     // MFMA C/D

__device__ __forceinline__ unsigned short f2bf(float f) {    // RTNE fp32->bf16
    unsigned u = __float_as_uint(f);
    u += 0x7FFFu + ((u >> 16) & 1u);
    return (unsigned short)(u >> 16);
}
__device__ __forceinline__ unsigned long long packwi(float w, int col) {
    // w > 0 always -> uint order == float order; low 32 bits = col ->
    // u64 min == (w, lowest col) lexicographic
    return ((unsigned long long)__float_as_uint(w) << 32) | (unsigned)col;
}
__device__ __forceinline__ float valof(unsigned long long p) {
    return __uint_as_float((unsigned)(p >> 32));
}

// ---------------- Kernel 1: row norms ||z_r||^2 (fp64 acc) + z -> bf16 conversion -----
__global__ __launch_bounds__(256) void z2_kernel(const float* __restrict__ z,
                                                 float* __restrict__ z2,
                                                 unsigned long long* __restrict__ zb8) {
    int row  = blockIdx.x * 4 + (threadIdx.x >> 6);
    int lane = threadIdx.x & 63;
    const float4* p = (const float4*)(z + (size_t)row * E_DIM);
    double s = 0.0;
#pragma unroll
    for (int it = 0; it < 2; ++it) {
        float4 v = p[lane + it * 64];
        s += (double)v.x * v.x + (double)v.y * v.y
           + (double)v.z * v.z + (double)v.w * v.w;
        unsigned long long pk =
              (unsigned long long)((unsigned)f2bf(v.x) | ((unsigned)f2bf(v.y) << 16))
            | ((unsigned long long)((unsigned)f2bf(v.z) | ((unsigned)f2bf(v.w) << 16)) << 32);
        zb8[(size_t)row * 128 + lane + it * 64] = pk;
    }
#pragma unroll
    for (int off = 32; off > 0; off >>= 1) s += __shfl_down(s, off);
    if (lane == 0) z2[row] = (float)s;
}

// ---------------- Kernel 1b: emb fp32 -> bf16 (RTNE), packed u64 stores ---------------
__global__ __launch_bounds__(256) void convb_kernel(const float* __restrict__ emb,
                                                    unsigned long long* __restrict__ embb8) {
    int t = blockIdx.x * 256 + threadIdx.x;     // 1,048,576 threads x 4 elems
    float4 v = ((const float4*)emb)[t];
    unsigned long long p =
          (unsigned long long)((unsigned)f2bf(v.x) | ((unsigned)f2bf(v.y) << 16))
        | ((unsigned long long)((unsigned)f2bf(v.z) | ((unsigned)f2bf(v.w) << 16)) << 32);
    embb8[t] = p;
}

// ---------------- Kernel 2: bf16 MFMA approx scores + per-128-col-group table ---------
// Approx w(r,n) = z2_r - 2*(bf16 z . bf16 e), fp32 MFMA accumulate. Per (row, group):
// packed u64 entry = w1_bits[63:32] | argmin_col[28:16] | delta_lb[15:0], where
// delta_lb = bf16-TRUNCATED (m2 - m1)  (round-down -> conservative scan flag).
// Rescore single-dots the stored argmin when w1 <= thr; fully rescans the group when
// w1 + delta_lb <= thr (i.e. 2nd-min possibly within margin) -- R7-validated semantics.
__global__ __launch_bounds__(512) void gemm_argmin_kernel(
        const unsigned short* __restrict__ zb,
        const unsigned short* __restrict__ embb,
        const float* __restrict__ z2s,
        unsigned long long* __restrict__ m1g) {
    __shared__ __align__(16) char smem[GBM * GBK * 2 + GBN * GBK * 2];  // 48 KB
    unsigned short* Al = (unsigned short*)smem;                 // 16 KB swizzled
    unsigned short* Bl = (unsigned short*)(smem + GBM * GBK * 2); // 32 KB swizzled
    __shared__ float z2sh[GBM];

    const int tid  = threadIdx.x;
    const int lane = tid & 63;
    const int wid  = tid >> 6;
    const int wr   = wid >> 2;          // 0..1 row half
    const int wc   = wid & 3;           // 0..3 col quarter (64 cols each)
    const int bx   = blockIdx.x & 31;   // 32 n-blocks
    const int by   = blockIdx.x >> 5;   // 256 row-blocks
    const int row0 = by * GBM;
    const int nb0  = bx * GBN;

    if (tid < GBM) z2sh[tid] = z2s[row0 + tid];

    // ---- staging geometry: 16B granules; A: 1024 granules (2/thread), B: 2048 (4/thread)
    const int cA   = tid * 2;
    const int rowA = cA >> 3;                    // 0..127
    const int grA  = cA & 7;                     // 0,2,4,6
    const unsigned short* gA = zb + (size_t)(row0 + rowA) * E_DIM + grA * 8;
    const int swA0 = rowA * 128 + (((grA    ) ^ (rowA & 7)) << 4);
    const int swA1 = rowA * 128 + (((grA + 1) ^ (rowA & 7)) << 4);

    const int cB   = tid * 4;
    const int rowB = cB >> 3;                    // 0..255
    const int grB  = cB & 7;                     // 0 or 4
    const unsigned short* gB = embb + (size_t)(nb0 + rowB) * E_DIM + grB * 8;
    const int swB0 = rowB * 128 + (((grB    ) ^ (rowB & 7)) << 4);
    const int swB1 = rowB * 128 + (((grB + 1) ^ (rowB & 7)) << 4);
    const int swB2 = rowB * 128 + (((grB + 2) ^ (rowB & 7)) << 4);
    const int swB3 = rowB * 128 + (((grB + 3) ^ (rowB & 7)) << 4);

    // ---- fragment read byte-offsets for kh=0; kh=1 is ^64 (granule+4 under the XOR)
    int aoff[4], boff[4];
#pragma unroll
    for (int ri = 0; ri < 4; ++ri) {
        int rowf = wr * 64 + ri * 16 + (lane & 15);
        aoff[ri] = rowf * 128 + (((lane >> 4) ^ (rowf & 7)) << 4);
    }
#pragma unroll
    for (int ci = 0; ci < 4; ++ci) {
        int rowf = wc * 64 + ci * 16 + (lane & 15);
        boff[ci] = rowf * 128 + (((lane >> 4) ^ (rowf & 7)) << 4);
    }

    f32x4 acc[4][4];
#pragma unroll
    for (int a = 0; a < 4; ++a)
#pragma unroll
        for (int b = 0; b < 4; ++b) acc[a][b] = (f32x4){0.f, 0.f, 0.f, 0.f};

    // ---- prologue: register-prefetch k-tile 0 (two-barrier structure, R1-proven)
    short8v pa0 = *(const short8v*)(gA + 0);
    short8v pa1 = *(const short8v*)(gA + 8);
    short8v pb0 = *(const short8v*)(gB + 0);
    short8v pb1 = *(const short8v*)(gB + 8);
    short8v pb2 = *(const short8v*)(gB + 16);
    short8v pb3 = *(const short8v*)(gB + 24);

    for (int kt = 0; kt < 8; ++kt) {
        *(short8v*)((char*)Al + swA0) = pa0;
        *(short8v*)((char*)Al + swA1) = pa1;
        *(short8v*)((char*)Bl + swB0) = pb0;
        *(short8v*)((char*)Bl + swB1) = pb1;
        *(short8v*)((char*)Bl + swB2) = pb2;
        *(short8v*)((char*)Bl + swB3) = pb3;
        __syncthreads();

        if (kt < 7) {
            const unsigned short* za = gA + (kt + 1) * GBK;
            pa0 = *(const short8v*)(za + 0);
            pa1 = *(const short8v*)(za + 8);
            const unsigned short* eb = gB + (kt + 1) * GBK;
            pb0 = *(const short8v*)(eb + 0);
            pb1 = *(const short8v*)(eb + 8);
            pb2 = *(const short8v*)(eb + 16);
            pb3 = *(const short8v*)(eb + 24);
        }

#pragma unroll
        for (int kh = 0; kh < 2; ++kh) {
            short8v af[4], bfr[4];
#pragma unroll
            for (int ri = 0; ri < 4; ++ri)
                af[ri] = *(const short8v*)((const char*)Al + (aoff[ri] ^ (kh << 6)));
#pragma unroll
            for (int ci = 0; ci < 4; ++ci)
                bfr[ci] = *(const short8v*)((const char*)Bl + (boff[ci] ^ (kh << 6)));
#pragma unroll
            for (int ri = 0; ri < 4; ++ri)
#pragma unroll
                for (int ci = 0; ci < 4; ++ci)
                    acc[ri][ci] = __builtin_amdgcn_mfma_f32_16x16x32_bf16(
                        af[ri], bfr[ci], acc[ri][ci], 0, 0, 0);
        }
        __syncthreads();
    }

    // ---- fold 1: per wave, (m1 packed, m2) over its 64 cols -> LDS (aliased on Al)
    unsigned long long* m1L = (unsigned long long*)smem;        // [128][4], 4 KB
    float*              m2L = (float*)(smem + 4096);            // [128][4], 2 KB
    const int colb = nb0 + wc * 64 + (lane & 15);
#pragma unroll
    for (int ri = 0; ri < 4; ++ri) {
#pragma unroll
        for (int i = 0; i < 4; ++i) {
            int row = wr * 64 + ri * 16 + ((lane >> 4) << 2) + i;
            float z2r = z2sh[row];
            float w0 = z2r - 2.f * acc[ri][0][i];
            float w1 = z2r - 2.f * acc[ri][1][i];
            float w2 = z2r - 2.f * acc[ri][2][i];
            float w3 = z2r - 2.f * acc[ri][3][i];
            unsigned long long m1 = packwi(w0, colb);
            float m2 = 3.4e38f;
            unsigned long long p;
            p = packwi(w1, colb + 16);
            if (p < m1) { m2 = valof(m1); m1 = p; } else m2 = fminf(m2, w1);
            p = packwi(w2, colb + 32);
            if (p < m1) { m2 = valof(m1); m1 = p; } else m2 = fminf(m2, w2);
            p = packwi(w3, colb + 48);
            if (p < m1) { m2 = valof(m1); m1 = p; } else m2 = fminf(m2, w3);
#pragma unroll
            for (int off = 1; off < 16; off <<= 1) {
                unsigned long long o1 = __shfl_xor(m1, off);
                float o2 = __shfl_xor(m2, off);
                float hi = fmaxf(valof(m1), valof(o1));
                m2 = fminf(fminf(m2, o2), hi);
                if (o1 < m1) m1 = o1;
            }
            if ((lane & 15) == ri * 4 + i) {
                m1L[row * 4 + wc] = m1;
                m2L[row * 4 + wc] = m2;
            }
        }
    }
    __syncthreads();

    // ---- fold 2: combine wave pairs (wc 0+1, 2+3) -> 128-col groups, pack, store
    if (tid < 256) {
        int row = tid >> 1, h = tid & 1;
        unsigned long long a = m1L[row * 4 + 2 * h];
        unsigned long long b = m1L[row * 4 + 2 * h + 1];
        float ma = m2L[row * 4 + 2 * h];
        float mb = m2L[row * 4 + 2 * h + 1];
        unsigned long long m1c = a < b ? a : b;
        float m2c = fminf(fminf(ma, mb), fmaxf(valof(a), valof(b)));
        float wv  = valof(m1c);
        unsigned col = (unsigned)(m1c & 0xFFFFu);               // global col < 8192
        unsigned dl  = __float_as_uint(m2c - wv) >> 16;         // bf16 trunc = round-down
        unsigned long long packed =
              ((unsigned long long)__float_as_uint(wv) << 32)
            | ((unsigned long long)col << 16) | dl;
        m1g[(size_t)(row0 + row) * NGROUPS + bx * 2 + h] = packed;
    }
}

// ---------------- Kernel 3: exact rescore of margin candidates -----------------------
// Reproduces the reference comparison EXACTLY: serial fp32 fma chain k=0..511 ascending,
// w = z2 - 2*acc (single rounding), ties -> lowest index.
__device__ __forceinline__ float exact_w(const float* zs, const float* __restrict__ emb,
                                         int col, float z2r) {
    const float* e = emb + (size_t)col * E_DIM;
    float acc = 0.f;
#pragma unroll 8
    for (int k = 0; k < E_DIM; ++k) acc = fmaf(zs[k], e[k], acc);
    return z2r - 2.f * acc;
}

__global__ __launch_bounds__(256) void rescore_kernel(
        const float* __restrict__ z, const float* __restrict__ emb,
        const float* __restrict__ z2s,
        const unsigned long long* __restrict__ m1g,
        float* __restrict__ idxf) {
    __shared__ __align__(16) float zsh[4][512];
    const int lane = threadIdx.x & 63;
    const int wid  = threadIdx.x >> 6;
    const int r    = blockIdx.x * 4 + wid;

    const float4* zr4 = (const float4*)(z + (size_t)r * E_DIM);
    ((float4*)zsh[wid])[lane]      = zr4[lane];
    ((float4*)zsh[wid])[lane + 64] = zr4[lane + 64];
    __syncthreads();
    const float* zs  = zsh[wid];
    const float  z2r = z2s[r];

    // one 128-col group per lane
    unsigned long long e = m1g[(size_t)r * NGROUPS + lane];
    float w1  = __uint_as_float((unsigned)(e >> 32));
    int   c1  = (int)((e >> 16) & 0xFFFFu);
    float dlb = __uint_as_float(((unsigned)e & 0xFFFFu) << 16);

    float gm = w1;
#pragma unroll
    for (int off = 1; off < 64; off <<= 1)
        gm = fminf(gm, __shfl_xor(gm, off));
    const float thr = gm + MARGIN;

    float wb = 3.4e38f; int ib = 0x7fffffff;
    if (w1 <= thr) {                             // group argmin candidate: single dot
        float w = exact_w(zs, emb, c1, z2r);
        if (w < wb || (w == wb && c1 < ib)) { wb = w; ib = c1; }
    }
    // full 128-col rescans for groups whose 2nd-min may be inside the margin
    unsigned long long mf = __ballot(w1 + dlb <= thr);
    while (mf) {
        int g = __ffsll((long long)mf) - 1; mf &= mf - 1;
        int col = g * 128 + lane;
        float w = exact_w(zs, emb, col, z2r);
        if (w < wb || (w == wb && col < ib)) { wb = w; ib = col; }
        col += 64;
        w = exact_w(zs, emb, col, z2r);
        if (w < wb || (w == wb && col < ib)) { wb = w; ib = col; }
    }
#pragma unroll
    for (int off = 1; off < 64; off <<= 1) {
        float wo = __shfl_xor(wb, off);
        int  io  = __shfl_xor(ib, off);
        if (wo < wb || (wo == wb && io < ib)) { wb = wo; ib = io; }
    }
    if (lane == 0) idxf[r] = (float)ib;
}

// ---------------- Kernel 4: gather + straight-through output + loss ----------------
__global__ __launch_bounds__(256) void output_kernel(const float* __restrict__ z,
                                                     const float* __restrict__ mask,
                                                     const float* __restrict__ emb,
                                                     const float* __restrict__ idxf,
                                                     float* __restrict__ out0,
                                                     float* __restrict__ loss) {
    const int nth = gridDim.x * blockDim.x;
    int t = blockIdx.x * blockDim.x + threadIdx.x;
    const float4* z4 = (const float4*)z;
    const float4* e4 = (const float4*)emb;
    float4* o4 = (float4*)out0;
    float partial = 0.f;
    for (int f = t; f < TOT_ELEMS / 4; f += nth) {
        int row = f >> 7;            // 128 float4 per 512-elem row
        int col = f & 127;
        int id  = (int)idxf[row];
        float m = mask[row];
        float4 zv = z4[f];
        float4 qv = e4[id * 128 + col];
        float dx = qv.x - zv.x, dy = qv.y - zv.y;
        float dz = qv.z - zv.z, dw = qv.w - zv.w;
        float4 ov;                   // z + (z_q - z): fp32 replication of ST estimator
        ov.x = zv.x + dx; ov.y = zv.y + dy;
        ov.z = zv.z + dz; ov.w = zv.w + dw;
        o4[f] = ov;
        partial += (dx * dx + dy * dy + dz * dz + dw * dw) * m;
    }
#pragma unroll
    for (int off = 32; off > 0; off >>= 1) partial += __shfl_down(partial, off);
    __shared__ float wsum[4];
    int lane = threadIdx.x & 63, w = threadIdx.x >> 6;
    if (lane == 0) wsum[w] = partial;
    __syncthreads();
    if (threadIdx.x == 0) {
        float s = wsum[0] + wsum[1] + wsum[2] + wsum[3];
        atomicAdd(loss, s * ((1.f + BETA) / (float)TOT_ELEMS));
    }
}

// ---------------- launcher -----------------------------------------------------------
// Scratch layout inside out0 (overwritten by output_kernel at the very end):
//   [0          .. 16,777,216)  m1g   u64[32768][64]    (packed group entries)
//   [16,777,216 .. 50,331,648)  zb    bf16[32768][512]
//   [50,331,648 .. 58,720,256)  embb  bf16[8192][512]
//   [58,720,256 .. 58,851,328)  z2    f32[32768]
extern "C" void kernel_launch(void* const* d_in, const int* in_sizes, int n_in,
                              void* d_out, int out_size, void* d_ws, size_t ws_size,
                              hipStream_t stream) {
    const float* z    = (const float*)d_in[0];   // (16,2048,512)
    const float* mask = (const float*)d_in[1];   // (16,2048)
    const float* emb  = (const float*)d_in[2];   // (8192,512)

    float* out0 = (float*)d_out;                 // z_q_st: 16777216 floats
    float* out1 = out0 + TOT_ELEMS;              // idx as float: 32768
    float* loss = out1 + NROWS;                  // scalar

    char* base = (char*)d_out;
    unsigned long long* m1g  = (unsigned long long*)base;
    unsigned short*     zb   = (unsigned short*)(base + 16777216);
    unsigned short*     embb = (unsigned short*)(base + 50331648);
    float*              z2st = (float*)(base + 58720256);

    hipMemsetAsync(loss, 0, sizeof(float), stream);
    z2_kernel<<<NROWS / 4, 256, 0, stream>>>(z, z2st, (unsigned long long*)zb);
    convb_kernel<<<4096, 256, 0, stream>>>(emb, (unsigned long long*)embb);
    gemm_argmin_kernel<<<(NROWS / GBM) * (N_E / GBN), 512, 0, stream>>>(
        zb, embb, z2st, m1g);
    rescore_kernel<<<NROWS / 4, 256, 0, stream>>>(z, emb, z2st, m1g, out1);
    output_kernel<<<4096, 256, 0, stream>>>(z, mask, emb, out1, out0, loss);
}

// Round 10
// 862.588 us; speedup vs baseline: 2.0206x; 1.0255x over previous
//
#include <hip/hip_runtime.h>

#define N_E 8192
#define E_DIM 512
#define NROWS 32768          // 16*2048
#define TOT_ELEMS 16777216   // 16*2048*512
#define BETA 0.25f

// ---- MFMA argmin GEMM geometry ----
#define GBM 128              // rows per block
#define GBN 256              // cols per block (4 waves x 64)
#define GBK 64               // k per tile (8 tiles cover K=512)
#define NGROUPS 64           // 8192 / 128-col groups
#define MARGIN 3.0e-4f       // >= 2*eps(bf16 approx); R7-validated (absmax 0.0)

typedef __attribute__((ext_vector_type(8))) short short8v;   // 8 bf16 (4 VGPR)
typedef __attribute__((ext_vector_type(4))) float f32x4;     // MFMA C/D

// async global->LDS DMA, 16B/lane; LDS dest = wave-uniform base + lane*16 (linear)
#define GLD16(gp, lp)                                                          \
    __builtin_amdgcn_global_load_lds(                                          \
        (const __attribute__((address_space(1))) void*)(gp),                   \
        (__attribute__((address_space(3))) void*)(lp), 16, 0, 0)

__device__ __forceinline__ unsigned short f2bf(float f) {    // RTNE fp32->bf16
    unsigned u = __float_as_uint(f);
    u += 0x7FFFu + ((u >> 16) & 1u);
    return (unsigned short)(u >> 16);
}
__device__ __forceinline__ unsigned long long packwi(float w, int col) {
    // w > 0 always -> uint order == float order; low 32 bits = col ->
    // u64 min == (w, lowest col) lexicographic
    return ((unsigned long long)__float_as_uint(w) << 32) | (unsigned)col;
}
__device__ __forceinline__ float valof(unsigned long long p) {
    return __uint_as_float((unsigned)(p >> 32));
}

// ---------------- Kernel 1: row norms ||z_r||^2 (fp64 acc) + z -> bf16 conversion -----
__global__ __launch_bounds__(256) void z2_kernel(const float* __restrict__ z,
                                                 float* __restrict__ z2,
                                                 unsigned long long* __restrict__ zb8) {
    int row  = blockIdx.x * 4 + (threadIdx.x >> 6);
    int lane = threadIdx.x & 63;
    const float4* p = (const float4*)(z + (size_t)row * E_DIM);
    double s = 0.0;
#pragma unroll
    for (int it = 0; it < 2; ++it) {
        float4 v = p[lane + it * 64];
        s += (double)v.x * v.x + (double)v.y * v.y
           + (double)v.z * v.z + (double)v.w * v.w;
        unsigned long long pk =
              (unsigned long long)((unsigned)f2bf(v.x) | ((unsigned)f2bf(v.y) << 16))
            | ((unsigned long long)((unsigned)f2bf(v.z) | ((unsigned)f2bf(v.w) << 16)) << 32);
        zb8[(size_t)row * 128 + lane + it * 64] = pk;
    }
#pragma unroll
    for (int off = 32; off > 0; off >>= 1) s += __shfl_down(s, off);
    if (lane == 0) z2[row] = (float)s;
}

// ---------------- Kernel 1b: emb fp32 -> bf16 (RTNE), packed u64 stores ---------------
__global__ __launch_bounds__(256) void convb_kernel(const float* __restrict__ emb,
                                                    unsigned long long* __restrict__ embb8) {
    int t = blockIdx.x * 256 + threadIdx.x;     // 1,048,576 threads x 4 elems
    float4 v = ((const float4*)emb)[t];
    unsigned long long p =
          (unsigned long long)((unsigned)f2bf(v.x) | ((unsigned)f2bf(v.y) << 16))
        | ((unsigned long long)((unsigned)f2bf(v.z) | ((unsigned)f2bf(v.w) << 16)) << 32);
    embb8[t] = p;
}

// ---------------- Kernel 2: bf16 MFMA approx scores + per-128-col-group table ---------
// Approx w(r,n) = z2_r - 2*(bf16 z . bf16 e), fp32 MFMA accumulate. Per (row, group):
// packed u64 entry = w1_bits[63:32] | argmin_col[28:16] | delta_lb[15:0] (bf16-trunc
// (m2-m1), round-down -> conservative scan flag). R9-validated semantics (absmax 0.0).
// R10: staging via global_load_lds (zero prefetch VGPRs, zero ds_writes). LDS dest is
// LINEAR; the XOR swizzle is applied on the per-lane GLOBAL source address (rule #21):
// LDS granule s of row r holds global k-granule s^(r&7); chunk = 8 rows = 64 granules,
// lane L -> row chunk*8+(L>>3), source granule (L&7)^((L>>3)&7). Read side unchanged.
// Register budget: ~40-56 VGPR + 64 acc <= 128 -> two blocks/CU co-resident again;
// the partner block's MFMA covers this block's vmcnt drain at each tile boundary.
__global__ __launch_bounds__(512) void gemm_argmin_kernel(
        const unsigned short* __restrict__ zb,
        const unsigned short* __restrict__ embb,
        const float* __restrict__ z2s,
        unsigned long long* __restrict__ m1g) {
    __shared__ __align__(16) char smem[GBM * GBK * 2 + GBN * GBK * 2];  // 48 KB
    unsigned short* Al = (unsigned short*)smem;                   // 16 KB
    unsigned short* Bl = (unsigned short*)(smem + GBM * GBK * 2); // 32 KB
    __shared__ float z2sh[GBM];

    const int tid  = threadIdx.x;
    const int lane = tid & 63;
    const int wid  = tid >> 6;
    const int wr   = wid >> 2;          // 0..1 row half
    const int wc   = wid & 3;           // 0..3 col quarter (64 cols each)
    const int bx   = blockIdx.x & 31;   // 32 n-blocks
    const int by   = blockIdx.x >> 5;   // 256 row-blocks
    const int row0 = by * GBM;
    const int nb0  = bx * GBN;

    if (tid < GBM) z2sh[tid] = z2s[row0 + tid];

    // ---- staging: per-lane swizzled global sources, linear LDS dests (wave-uniform)
    const int lrow = lane >> 3;                        // lane's row within an 8-row chunk
    const int lswz = ((lane & 7) ^ (lrow & 7)) * 8;    // swizzled k-granule (ushorts)
    // A: 16 chunks of 1KB, wave wv owns {2wv, 2wv+1}
    const unsigned short* srcA0 = zb + (size_t)(row0 + wid * 16 + lrow) * E_DIM + lswz;
    const unsigned short* srcA1 = srcA0 + 8 * E_DIM;
    unsigned short* dstA0 = Al + (wid * 2) * 512;
    unsigned short* dstA1 = dstA0 + 512;
    // B: 32 chunks of 1KB, wave wv owns {4wv .. 4wv+3}
    const unsigned short* srcB0 = embb + (size_t)(nb0 + wid * 32 + lrow) * E_DIM + lswz;
    const unsigned short* srcB1 = srcB0 + 8 * E_DIM;
    const unsigned short* srcB2 = srcB0 + 16 * E_DIM;
    const unsigned short* srcB3 = srcB0 + 24 * E_DIM;
    unsigned short* dstB0 = Bl + (wid * 4) * 512;
    unsigned short* dstB1 = dstB0 + 512;
    unsigned short* dstB2 = dstB0 + 1024;
    unsigned short* dstB3 = dstB0 + 1536;

    // ---- fragment read byte-offsets for kh=0; kh=1 is ^64 (granule+4 under the XOR)
    int aoff[4], boff[4];
#pragma unroll
    for (int ri = 0; ri < 4; ++ri) {
        int rowf = wr * 64 + ri * 16 + (lane & 15);
        aoff[ri] = rowf * 128 + (((lane >> 4) ^ (rowf & 7)) << 4);
    }
#pragma unroll
    for (int ci = 0; ci < 4; ++ci) {
        int rowf = wc * 64 + ci * 16 + (lane & 15);
        boff[ci] = rowf * 128 + (((lane >> 4) ^ (rowf & 7)) << 4);
    }

    f32x4 acc[4][4];
#pragma unroll
    for (int a = 0; a < 4; ++a)
#pragma unroll
        for (int b = 0; b < 4; ++b) acc[a][b] = (f32x4){0.f, 0.f, 0.f, 0.f};

#pragma unroll
    for (int kt = 0; kt < 8; ++kt) {
        // ---- stage tile kt: async DMA, kt*GBK folds into the offset immediate
        GLD16(srcA0 + kt * GBK, dstA0);
        GLD16(srcA1 + kt * GBK, dstA1);
        GLD16(srcB0 + kt * GBK, dstB0);
        GLD16(srcB1 + kt * GBK, dstB1);
        GLD16(srcB2 + kt * GBK, dstB2);
        GLD16(srcB3 + kt * GBK, dstB3);
        __syncthreads();   // drains vmcnt: tile resident

        // ---- compute: 2 k-halves x 4x4 fragments = 32 MFMA
#pragma unroll
        for (int kh = 0; kh < 2; ++kh) {
            short8v af[4], bfr[4];
#pragma unroll
            for (int ri = 0; ri < 4; ++ri)
                af[ri] = *(const short8v*)((const char*)Al + (aoff[ri] ^ (kh << 6)));
#pragma unroll
            for (int ci = 0; ci < 4; ++ci)
                bfr[ci] = *(const short8v*)((const char*)Bl + (boff[ci] ^ (kh << 6)));
#pragma unroll
            for (int ri = 0; ri < 4; ++ri)
#pragma unroll
                for (int ci = 0; ci < 4; ++ci)
                    acc[ri][ci] = __builtin_amdgcn_mfma_f32_16x16x32_bf16(
                        af[ri], bfr[ci], acc[ri][ci], 0, 0, 0);
        }
        __syncthreads();   // reads done -> next tile's DMA may overwrite
    }

    // ---- fold 1: per wave, (m1 packed, m2) over its 64 cols -> LDS (aliased on Al)
    unsigned long long* m1L = (unsigned long long*)smem;        // [128][4], 4 KB
    float*              m2L = (float*)(smem + 4096);            // [128][4], 2 KB
    const int colb = nb0 + wc * 64 + (lane & 15);
#pragma unroll
    for (int ri = 0; ri < 4; ++ri) {
#pragma unroll
        for (int i = 0; i < 4; ++i) {
            int row = wr * 64 + ri * 16 + ((lane >> 4) << 2) + i;
            float z2r = z2sh[row];
            float w0 = z2r - 2.f * acc[ri][0][i];
            float w1 = z2r - 2.f * acc[ri][1][i];
            float w2 = z2r - 2.f * acc[ri][2][i];
            float w3 = z2r - 2.f * acc[ri][3][i];
            unsigned long long m1 = packwi(w0, colb);
            float m2 = 3.4e38f;
            unsigned long long p;
            p = packwi(w1, colb + 16);
            if (p < m1) { m2 = valof(m1); m1 = p; } else m2 = fminf(m2, w1);
            p = packwi(w2, colb + 32);
            if (p < m1) { m2 = valof(m1); m1 = p; } else m2 = fminf(m2, w2);
            p = packwi(w3, colb + 48);
            if (p < m1) { m2 = valof(m1); m1 = p; } else m2 = fminf(m2, w3);
#pragma unroll
            for (int off = 1; off < 16; off <<= 1) {
                unsigned long long o1 = __shfl_xor(m1, off);
                float o2 = __shfl_xor(m2, off);
                float hi = fmaxf(valof(m1), valof(o1));
                m2 = fminf(fminf(m2, o2), hi);
                if (o1 < m1) m1 = o1;
            }
            if ((lane & 15) == ri * 4 + i) {
                m1L[row * 4 + wc] = m1;
                m2L[row * 4 + wc] = m2;
            }
        }
    }
    __syncthreads();

    // ---- fold 2: combine wave pairs (wc 0+1, 2+3) -> 128-col groups, pack, store
    if (tid < 256) {
        int row = tid >> 1, h = tid & 1;
        unsigned long long a = m1L[row * 4 + 2 * h];
        unsigned long long b = m1L[row * 4 + 2 * h + 1];
        float ma = m2L[row * 4 + 2 * h];
        float mb = m2L[row * 4 + 2 * h + 1];
        unsigned long long m1c = a < b ? a : b;
        float m2c = fminf(fminf(ma, mb), fmaxf(valof(a), valof(b)));
        float wv  = valof(m1c);
        unsigned col = (unsigned)(m1c & 0xFFFFu);               // global col < 8192
        unsigned dl  = __float_as_uint(m2c - wv) >> 16;         // bf16 trunc = round-down
        unsigned long long packed =
              ((unsigned long long)__float_as_uint(wv) << 32)
            | ((unsigned long long)col << 16) | dl;
        m1g[(size_t)(row0 + row) * NGROUPS + bx * 2 + h] = packed;
    }
}

// ---------------- Kernel 3: exact rescore of margin candidates -----------------------
// Reproduces the reference comparison EXACTLY: serial fp32 fma chain k=0..511 ascending,
// w = z2 - 2*acc (single rounding), ties -> lowest index.
__device__ __forceinline__ float exact_w(const float* zs, const float* __restrict__ emb,
                                         int col, float z2r) {
    const float* e = emb + (size_t)col * E_DIM;
    float acc = 0.f;
#pragma unroll 8
    for (int k = 0; k < E_DIM; ++k) acc = fmaf(zs[k], e[k], acc);
    return z2r - 2.f * acc;
}

__global__ __launch_bounds__(256) void rescore_kernel(
        const float* __restrict__ z, const float* __restrict__ emb,
        const float* __restrict__ z2s,
        const unsigned long long* __restrict__ m1g,
        float* __restrict__ idxf) {
    __shared__ __align__(16) float zsh[4][512];
    const int lane = threadIdx.x & 63;
    const int wid  = threadIdx.x >> 6;
    const int r    = blockIdx.x * 4 + wid;

    const float4* zr4 = (const float4*)(z + (size_t)r * E_DIM);
    ((float4*)zsh[wid])[lane]      = zr4[lane];
    ((float4*)zsh[wid])[lane + 64] = zr4[lane + 64];
    __syncthreads();
    const float* zs  = zsh[wid];
    const float  z2r = z2s[r];

    // one 128-col group per lane
    unsigned long long e = m1g[(size_t)r * NGROUPS + lane];
    float w1  = __uint_as_float((unsigned)(e >> 32));
    int   c1  = (int)((e >> 16) & 0xFFFFu);
    float dlb = __uint_as_float(((unsigned)e & 0xFFFFu) << 16);

    float gm = w1;
#pragma unroll
    for (int off = 1; off < 64; off <<= 1)
        gm = fminf(gm, __shfl_xor(gm, off));
    const float thr = gm + MARGIN;

    float wb = 3.4e38f; int ib = 0x7fffffff;
    if (w1 <= thr) {                             // group argmin candidate: single dot
        float w = exact_w(zs, emb, c1, z2r);
        if (w < wb || (w == wb && c1 < ib)) { wb = w; ib = c1; }
    }
    // full 128-col rescans for groups whose 2nd-min may be inside the margin
    unsigned long long mf = __ballot(w1 + dlb <= thr);
    while (mf) {
        int g = __ffsll((long long)mf) - 1; mf &= mf - 1;
        int col = g * 128 + lane;
        float w = exact_w(zs, emb, col, z2r);
        if (w < wb || (w == wb && col < ib)) { wb = w; ib = col; }
        col += 64;
        w = exact_w(zs, emb, col, z2r);
        if (w < wb || (w == wb && col < ib)) { wb = w; ib = col; }
    }
#pragma unroll
    for (int off = 1; off < 64; off <<= 1) {
        float wo = __shfl_xor(wb, off);
        int  io  = __shfl_xor(ib, off);
        if (wo < wb || (wo == wb && io < ib)) { wb = wo; ib = io; }
    }
    if (lane == 0) idxf[r] = (float)ib;
}

// ---------------- Kernel 4: gather + straight-through output + loss ----------------
__global__ __launch_bounds__(256) void output_kernel(const float* __restrict__ z,
                                                     const float* __restrict__ mask,
                                                     const float* __restrict__ emb,
                                                     const float* __restrict__ idxf,
                                                     float* __restrict__ out0,
                                                     float* __restrict__ loss) {
    const int nth = gridDim.x * blockDim.x;
    int t = blockIdx.x * blockDim.x + threadIdx.x;
    const float4* z4 = (const float4*)z;
    const float4* e4 = (const float4*)emb;
    float4* o4 = (float4*)out0;
    float partial = 0.f;
    for (int f = t; f < TOT_ELEMS / 4; f += nth) {
        int row = f >> 7;            // 128 float4 per 512-elem row
        int col = f & 127;
        int id  = (int)idxf[row];
        float m = mask[row];
        float4 zv = z4[f];
        float4 qv = e4[id * 128 + col];
        float dx = qv.x - zv.x, dy = qv.y - zv.y;
        float dz = qv.z - zv.z, dw = qv.w - zv.w;
        float4 ov;                   // z + (z_q - z): fp32 replication of ST estimator
        ov.x = zv.x + dx; ov.y = zv.y + dy;
        ov.z = zv.z + dz; ov.w = zv.w + dw;
        o4[f] = ov;
        partial += (dx * dx + dy * dy + dz * dz + dw * dw) * m;
    }
#pragma unroll
    for (int off = 32; off > 0; off >>= 1) partial += __shfl_down(partial, off);
    __shared__ float wsum[4];
    int lane = threadIdx.x & 63, w = threadIdx.x >> 6;
    if (lane == 0) wsum[w] = partial;
    __syncthreads();
    if (threadIdx.x == 0) {
        float s = wsum[0] + wsum[1] + wsum[2] + wsum[3];
        atomicAdd(loss, s * ((1.f + BETA) / (float)TOT_ELEMS));
    }
}

// ---------------- launcher -----------------------------------------------------------
// Scratch layout inside out0 (overwritten by output_kernel at the very end):
//   [0          .. 16,777,216)  m1g   u64[32768][64]    (packed group entries)
//   [16,777,216 .. 50,331,648)  zb    bf16[32768][512]
//   [50,331,648 .. 58,720,256)  embb  bf16[8192][512]
//   [58,720,256 .. 58,851,328)  z2    f32[32768]
extern "C" void kernel_launch(void* const* d_in, const int* in_sizes, int n_in,
                              void* d_out, int out_size, void* d_ws, size_t ws_size,
                              hipStream_t stream) {
    const float* z    = (const float*)d_in[0];   // (16,2048,512)
    const float* mask = (const float*)d_in[1];   // (16,2048)
    const float* emb  = (const float*)d_in[2];   // (8192,512)

    float* out0 = (float*)d_out;                 // z_q_st: 16777216 floats
    float* out1 = out0 + TOT_ELEMS;              // idx as float: 32768
    float* loss = out1 + NROWS;                  // scalar

    char* base = (char*)d_out;
    unsigned long long* m1g  = (unsigned long long*)base;
    unsigned short*     zb   = (unsigned short*)(base + 16777216);
    unsigned short*     embb = (unsigned short*)(base + 50331648);
    float*              z2st = (float*)(base + 58720256);

    hipMemsetAsync(loss, 0, sizeof(float), stream);
    z2_kernel<<<NROWS / 4, 256, 0, stream>>>(z, z2st, (unsigned long long*)zb);
    convb_kernel<<<4096, 256, 0, stream>>>(emb, (unsigned long long*)embb);
    gemm_argmin_kernel<<<(NROWS / GBM) * (N_E / GBN), 512, 0, stream>>>(
        zb, embb, z2st, m1g);
    rescore_kernel<<<NROWS / 4, 256, 0, stream>>>(z, emb, z2st, m1g, out1);
    output_kernel<<<4096, 256, 0, stream>>>(z, mask, emb, out1, out0, loss);
}

// Round 11
// 848.097 us; speedup vs baseline: 2.0552x; 1.0171x over previous
//
#include <hip/hip_runtime.h>

#define N_E 8192
#define E_DIM 512
#define NROWS 32768          // 16*2048
#define TOT_ELEMS 16777216   // 16*2048*512
#define BETA 0.25f

// ---- MFMA argmin GEMM geometry ----
#define GBM 128              // rows per block
#define GBN 256              // cols per block
#define GBK 64               // k per tile (8 tiles cover K=512)
#define NGROUPS 64           // 8192 / 128-col groups
#define MARGIN 3.0e-4f       // >= 2*eps(bf16 approx); R7-validated (absmax 0.0)

typedef __attribute__((ext_vector_type(8))) short short8v;   // 8 bf16 (4 VGPR)
typedef __attribute__((ext_vector_type(4))) float f32x4;     // MFMA C/D

// async global->LDS DMA, 16B/lane; LDS dest = wave-uniform base + lane*16 (linear)
#define GLD16(gp, lp)                                                          \
    __builtin_amdgcn_global_load_lds(                                          \
        (const __attribute__((address_space(1))) void*)(gp),                   \
        (__attribute__((address_space(3))) void*)(lp), 16, 0, 0)

__device__ __forceinline__ unsigned short f2bf(float f) {    // RTNE fp32->bf16
    unsigned u = __float_as_uint(f);
    u += 0x7FFFu + ((u >> 16) & 1u);
    return (unsigned short)(u >> 16);
}
__device__ __forceinline__ unsigned long long packwi(float w, int col) {
    // w > 0 always -> uint order == float order; low 32 bits = col ->
    // u64 min == (w, lowest col) lexicographic
    return ((unsigned long long)__float_as_uint(w) << 32) | (unsigned)col;
}
__device__ __forceinline__ float valof(unsigned long long p) {
    return __uint_as_float((unsigned)(p >> 32));
}

// ---------------- Kernel 1: row norms ||z_r||^2 (fp64 acc) + z -> bf16 conversion -----
__global__ __launch_bounds__(256) void z2_kernel(const float* __restrict__ z,
                                                 float* __restrict__ z2,
                                                 unsigned long long* __restrict__ zb8) {
    int row  = blockIdx.x * 4 + (threadIdx.x >> 6);
    int lane = threadIdx.x & 63;
    const float4* p = (const float4*)(z + (size_t)row * E_DIM);
    double s = 0.0;
#pragma unroll
    for (int it = 0; it < 2; ++it) {
        float4 v = p[lane + it * 64];
        s += (double)v.x * v.x + (double)v.y * v.y
           + (double)v.z * v.z + (double)v.w * v.w;
        unsigned long long pk =
              (unsigned long long)((unsigned)f2bf(v.x) | ((unsigned)f2bf(v.y) << 16))
            | ((unsigned long long)((unsigned)f2bf(v.z) | ((unsigned)f2bf(v.w) << 16)) << 32);
        zb8[(size_t)row * 128 + lane + it * 64] = pk;
    }
#pragma unroll
    for (int off = 32; off > 0; off >>= 1) s += __shfl_down(s, off);
    if (lane == 0) z2[row] = (float)s;
}

// ---------------- Kernel 1b: emb fp32 -> bf16 (RTNE), packed u64 stores ---------------
__global__ __launch_bounds__(256) void convb_kernel(const float* __restrict__ emb,
                                                    unsigned long long* __restrict__ embb8) {
    int t = blockIdx.x * 256 + threadIdx.x;     // 1,048,576 threads x 4 elems
    float4 v = ((const float4*)emb)[t];
    unsigned long long p =
          (unsigned long long)((unsigned)f2bf(v.x) | ((unsigned)f2bf(v.y) << 16))
        | ((unsigned long long)((unsigned)f2bf(v.z) | ((unsigned)f2bf(v.w) << 16)) << 32);
    embb8[t] = p;
}

// ---------------- Kernel 2: bf16 MFMA approx scores + per-128-col-group table ---------
// Approx w(r,n) = z2_r - 2*(bf16 z . bf16 e), fp32 MFMA accumulate. Per (row, group):
// packed u64 entry = w1_bits[63:32] | argmin_col[28:16] | delta_lb[15:0] (bf16-trunc
// (m2-m1), round-down -> conservative scan flag). R9/R10-validated (absmax 0.0).
// R11: 16 waves (1024 thr), wave tile 32 rows x 64 cols -> acc = 2x4 frags = 32 regs
// (was 64). Unified-file total drops ~140 -> ~100: R10's occupancy was pinned at 1
// block/CU because VGPR(76) + acc(64) = 140 > 128 (the 4-waves/SIMD boundary).
// Same block tile, same staging (global_load_lds, pre-swizzled source, linear dest),
// same table semantics; only the wave decomposition and fold-1 row indexing change.
__global__ __launch_bounds__(1024, 4) void gemm_argmin_kernel(
        const unsigned short* __restrict__ zb,
        const unsigned short* __restrict__ embb,
        const float* __restrict__ z2s,
        unsigned long long* __restrict__ m1g) {
    __shared__ __align__(16) char smem[GBM * GBK * 2 + GBN * GBK * 2];  // 48 KB
    unsigned short* Al = (unsigned short*)smem;                   // 16 KB
    unsigned short* Bl = (unsigned short*)(smem + GBM * GBK * 2); // 32 KB
    __shared__ float z2sh[GBM];

    const int tid  = threadIdx.x;
    const int lane = tid & 63;
    const int wid  = tid >> 6;          // 0..15
    const int wr   = wid >> 2;          // 0..3: 32-row band
    const int wc   = wid & 3;           // 0..3: 64-col quarter
    const int bx   = blockIdx.x & 31;   // 32 n-blocks
    const int by   = blockIdx.x >> 5;   // 256 row-blocks
    const int row0 = by * GBM;
    const int nb0  = bx * GBN;

    if (tid < GBM) z2sh[tid] = z2s[row0 + tid];

    // ---- staging: per-lane swizzled global sources, linear LDS dests (1 A + 2 B /wave)
    const int lrow = lane >> 3;                        // lane's row within an 8-row chunk
    const int lswz = ((lane & 7) ^ lrow) * 8;          // swizzled k-granule (ushorts)
    const unsigned short* srcA  = zb   + (size_t)(row0 + wid * 8  + lrow) * E_DIM + lswz;
    const unsigned short* srcB0 = embb + (size_t)(nb0 + wid * 16 + lrow) * E_DIM + lswz;
    const unsigned short* srcB1 = srcB0 + 8 * E_DIM;
    unsigned short* dstA  = Al + wid * 512;
    unsigned short* dstB0 = Bl + wid * 1024;
    unsigned short* dstB1 = dstB0 + 512;

    // ---- fragment read byte-offsets (rowf&7 == lane&7 for all fragments -> the
    //      ri/ci*2048 deltas are compile-time immediates; kh=1 is ^64)
    const int swz = ((lane >> 4) ^ (lane & 7)) << 4;
    const int aof  = (wr * 32 + (lane & 15)) * 128 + swz;
    const int bof  = (wc * 64 + (lane & 15)) * 128 + swz;
    const int aof1 = aof ^ 64;
    const int bof1 = bof ^ 64;

    f32x4 acc[2][4];
#pragma unroll
    for (int a = 0; a < 2; ++a)
#pragma unroll
        for (int b = 0; b < 4; ++b) acc[a][b] = (f32x4){0.f, 0.f, 0.f, 0.f};

#pragma unroll
    for (int kt = 0; kt < 8; ++kt) {
        // ---- stage tile kt: async DMA, kt*GBK folds into the offset immediate
        GLD16(srcA  + kt * GBK, dstA);
        GLD16(srcB0 + kt * GBK, dstB0);
        GLD16(srcB1 + kt * GBK, dstB1);
        __syncthreads();   // drains vmcnt: tile resident

        // ---- compute: 2 k-halves x (2 row x 4 col) fragments = 16 MFMA
#pragma unroll
        for (int kh = 0; kh < 2; ++kh) {
            const int ak = kh ? aof1 : aof;
            const int bk = kh ? bof1 : bof;
            short8v a0 = *(const short8v*)((const char*)Al + ak);
            short8v a1 = *(const short8v*)((const char*)Al + ak + 2048);
            short8v b0 = *(const short8v*)((const char*)Bl + bk);
            short8v b1 = *(const short8v*)((const char*)Bl + bk + 2048);
            short8v b2 = *(const short8v*)((const char*)Bl + bk + 4096);
            short8v b3 = *(const short8v*)((const char*)Bl + bk + 6144);
            acc[0][0] = __builtin_amdgcn_mfma_f32_16x16x32_bf16(a0, b0, acc[0][0], 0, 0, 0);
            acc[0][1] = __builtin_amdgcn_mfma_f32_16x16x32_bf16(a0, b1, acc[0][1], 0, 0, 0);
            acc[0][2] = __builtin_amdgcn_mfma_f32_16x16x32_bf16(a0, b2, acc[0][2], 0, 0, 0);
            acc[0][3] = __builtin_amdgcn_mfma_f32_16x16x32_bf16(a0, b3, acc[0][3], 0, 0, 0);
            acc[1][0] = __builtin_amdgcn_mfma_f32_16x16x32_bf16(a1, b0, acc[1][0], 0, 0, 0);
            acc[1][1] = __builtin_amdgcn_mfma_f32_16x16x32_bf16(a1, b1, acc[1][1], 0, 0, 0);
            acc[1][2] = __builtin_amdgcn_mfma_f32_16x16x32_bf16(a1, b2, acc[1][2], 0, 0, 0);
            acc[1][3] = __builtin_amdgcn_mfma_f32_16x16x32_bf16(a1, b3, acc[1][3], 0, 0, 0);
        }
        __syncthreads();   // reads done -> next tile's DMA may overwrite
    }

    // ---- fold 1: per wave, (m1 packed, m2) over its 64 cols -> LDS (aliased on Al)
    unsigned long long* m1L = (unsigned long long*)smem;        // [128][4], 4 KB
    float*              m2L = (float*)(smem + 4096);            // [128][4], 2 KB
    const int colb = nb0 + wc * 64 + (lane & 15);
#pragma unroll
    for (int ri = 0; ri < 2; ++ri) {
#pragma unroll
        for (int i = 0; i < 4; ++i) {
            int row = wr * 32 + ri * 16 + ((lane >> 4) << 2) + i;
            float z2r = z2sh[row];
            float w0 = z2r - 2.f * acc[ri][0][i];
            float w1 = z2r - 2.f * acc[ri][1][i];
            float w2 = z2r - 2.f * acc[ri][2][i];
            float w3 = z2r - 2.f * acc[ri][3][i];
            unsigned long long m1 = packwi(w0, colb);
            float m2 = 3.4e38f;
            unsigned long long p;
            p = packwi(w1, colb + 16);
            if (p < m1) { m2 = valof(m1); m1 = p; } else m2 = fminf(m2, w1);
            p = packwi(w2, colb + 32);
            if (p < m1) { m2 = valof(m1); m1 = p; } else m2 = fminf(m2, w2);
            p = packwi(w3, colb + 48);
            if (p < m1) { m2 = valof(m1); m1 = p; } else m2 = fminf(m2, w3);
#pragma unroll
            for (int off = 1; off < 16; off <<= 1) {
                unsigned long long o1 = __shfl_xor(m1, off);
                float o2 = __shfl_xor(m2, off);
                float hi = fmaxf(valof(m1), valof(o1));
                m2 = fminf(fminf(m2, o2), hi);
                if (o1 < m1) m1 = o1;
            }
            if ((lane & 15) == ri * 4 + i) {
                m1L[row * 4 + wc] = m1;
                m2L[row * 4 + wc] = m2;
            }
        }
    }
    __syncthreads();

    // ---- fold 2: combine wave pairs (wc 0+1, 2+3) -> 128-col groups, pack, store
    if (tid < 256) {
        int row = tid >> 1, h = tid & 1;
        unsigned long long a = m1L[row * 4 + 2 * h];
        unsigned long long b = m1L[row * 4 + 2 * h + 1];
        float ma = m2L[row * 4 + 2 * h];
        float mb = m2L[row * 4 + 2 * h + 1];
        unsigned long long m1c = a < b ? a : b;
        float m2c = fminf(fminf(ma, mb), fmaxf(valof(a), valof(b)));
        float wv  = valof(m1c);
        unsigned col = (unsigned)(m1c & 0xFFFFu);               // global col < 8192
        unsigned dl  = __float_as_uint(m2c - wv) >> 16;         // bf16 trunc = round-down
        unsigned long long packed =
              ((unsigned long long)__float_as_uint(wv) << 32)
            | ((unsigned long long)col << 16) | dl;
        m1g[(size_t)(row0 + row) * NGROUPS + bx * 2 + h] = packed;
    }
}

// ---------------- Kernel 3: exact rescore of margin candidates -----------------------
// Reproduces the reference comparison EXACTLY: serial fp32 fma chain k=0..511 ascending,
// w = z2 - 2*acc (single rounding), ties -> lowest index.
__device__ __forceinline__ float exact_w(const float* zs, const float* __restrict__ emb,
                                         int col, float z2r) {
    const float* e = emb + (size_t)col * E_DIM;
    float acc = 0.f;
#pragma unroll 8
    for (int k = 0; k < E_DIM; ++k) acc = fmaf(zs[k], e[k], acc);
    return z2r - 2.f * acc;
}

__global__ __launch_bounds__(256) void rescore_kernel(
        const float* __restrict__ z, const float* __restrict__ emb,
        const float* __restrict__ z2s,
        const unsigned long long* __restrict__ m1g,
        float* __restrict__ idxf) {
    __shared__ __align__(16) float zsh[4][512];
    const int lane = threadIdx.x & 63;
    const int wid  = threadIdx.x >> 6;
    const int r    = blockIdx.x * 4 + wid;

    const float4* zr4 = (const float4*)(z + (size_t)r * E_DIM);
    ((float4*)zsh[wid])[lane]      = zr4[lane];
    ((float4*)zsh[wid])[lane + 64] = zr4[lane + 64];
    __syncthreads();
    const float* zs  = zsh[wid];
    const float  z2r = z2s[r];

    // one 128-col group per lane
    unsigned long long e = m1g[(size_t)r * NGROUPS + lane];
    float w1  = __uint_as_float((unsigned)(e >> 32));
    int   c1  = (int)((e >> 16) & 0xFFFFu);
    float dlb = __uint_as_float(((unsigned)e & 0xFFFFu) << 16);

    float gm = w1;
#pragma unroll
    for (int off = 1; off < 64; off <<= 1)
        gm = fminf(gm, __shfl_xor(gm, off));
    const float thr = gm + MARGIN;

    float wb = 3.4e38f; int ib = 0x7fffffff;
    if (w1 <= thr) {                             // group argmin candidate: single dot
        float w = exact_w(zs, emb, c1, z2r);
        if (w < wb || (w == wb && c1 < ib)) { wb = w; ib = c1; }
    }
    // full 128-col rescans for groups whose 2nd-min may be inside the margin
    unsigned long long mf = __ballot(w1 + dlb <= thr);
    while (mf) {
        int g = __ffsll((long long)mf) - 1; mf &= mf - 1;
        int col = g * 128 + lane;
        float w = exact_w(zs, emb, col, z2r);
        if (w < wb || (w == wb && col < ib)) { wb = w; ib = col; }
        col += 64;
        w = exact_w(zs, emb, col, z2r);
        if (w < wb || (w == wb && col < ib)) { wb = w; ib = col; }
    }
#pragma unroll
    for (int off = 1; off < 64; off <<= 1) {
        float wo = __shfl_xor(wb, off);
        int  io  = __shfl_xor(ib, off);
        if (wo < wb || (wo == wb && io < ib)) { wb = wo; ib = io; }
    }
    if (lane == 0) idxf[r] = (float)ib;
}

// ---------------- Kernel 4: gather + straight-through output + loss ----------------
__global__ __launch_bounds__(256) void output_kernel(const float* __restrict__ z,
                                                     const float* __restrict__ mask,
                                                     const float* __restrict__ emb,
                                                     const float* __restrict__ idxf,
                                                     float* __restrict__ out0,
                                                     float* __restrict__ loss) {
    const int nth = gridDim.x * blockDim.x;
    int t = blockIdx.x * blockDim.x + threadIdx.x;
    const float4* z4 = (const float4*)z;
    const float4* e4 = (const float4*)emb;
    float4* o4 = (float4*)out0;
    float partial = 0.f;
    for (int f = t; f < TOT_ELEMS / 4; f += nth) {
        int row = f >> 7;            // 128 float4 per 512-elem row
        int col = f & 127;
        int id  = (int)idxf[row];
        float m = mask[row];
        float4 zv = z4[f];
        float4 qv = e4[id * 128 + col];
        float dx = qv.x - zv.x, dy = qv.y - zv.y;
        float dz = qv.z - zv.z, dw = qv.w - zv.w;
        float4 ov;                   // z + (z_q - z): fp32 replication of ST estimator
        ov.x = zv.x + dx; ov.y = zv.y + dy;
        ov.z = zv.z + dz; ov.w = zv.w + dw;
        o4[f] = ov;
        partial += (dx * dx + dy * dy + dz * dz + dw * dw) * m;
    }
#pragma unroll
    for (int off = 32; off > 0; off >>= 1) partial += __shfl_down(partial, off);
    __shared__ float wsum[4];
    int lane = threadIdx.x & 63, w = threadIdx.x >> 6;
    if (lane == 0) wsum[w] = partial;
    __syncthreads();
    if (threadIdx.x == 0) {
        float s = wsum[0] + wsum[1] + wsum[2] + wsum[3];
        atomicAdd(loss, s * ((1.f + BETA) / (float)TOT_ELEMS));
    }
}

// ---------------- launcher -----------------------------------------------------------
// Scratch layout inside out0 (overwritten by output_kernel at the very end):
//   [0          .. 16,777,216)  m1g   u64[32768][64]    (packed group entries)
//   [16,777,216 .. 50,331,648)  zb    bf16[32768][512]
//   [50,331,648 .. 58,720,256)  embb  bf16[8192][512]
//   [58,720,256 .. 58,851,328)  z2    f32[32768]
extern "C" void kernel_launch(void* const* d_in, const int* in_sizes, int n_in,
                              void* d_out, int out_size, void* d_ws, size_t ws_size,
                              hipStream_t stream) {
    const float* z    = (const float*)d_in[0];   // (16,2048,512)
    const float* mask = (const float*)d_in[1];   // (16,2048)
    const float* emb  = (const float*)d_in[2];   // (8192,512)

    float* out0 = (float*)d_out;                 // z_q_st: 16777216 floats
    float* out1 = out0 + TOT_ELEMS;              // idx as float: 32768
    float* loss = out1 + NROWS;                  // scalar

    char* base = (char*)d_out;
    unsigned long long* m1g  = (unsigned long long*)base;
    unsigned short*     zb   = (unsigned short*)(base + 16777216);
    unsigned short*     embb = (unsigned short*)(base + 50331648);
    float*              z2st = (float*)(base + 58720256);

    hipMemsetAsync(loss, 0, sizeof(float), stream);
    z2_kernel<<<NROWS / 4, 256, 0, stream>>>(z, z2st, (unsigned long long*)zb);
    convb_kernel<<<4096, 256, 0, stream>>>(emb, (unsigned long long*)embb);
    gemm_argmin_kernel<<<(NROWS / GBM) * (N_E / GBN), 1024, 0, stream>>>(
        zb, embb, z2st, m1g);
    rescore_kernel<<<NROWS / 4, 256, 0, stream>>>(z, emb, z2st, m1g, out1);
    output_kernel<<<4096, 256, 0, stream>>>(z, mask, emb, out1, out0, loss);
}

// Round 12
// 779.540 us; speedup vs baseline: 2.2359x; 1.0879x over previous
//
#include <hip/hip_runtime.h>

#define N_E 8192
#define E_DIM 512
#define NROWS 32768          // 16*2048
#define TOT_ELEMS 16777216   // 16*2048*512
#define BETA 0.25f

// ---- MFMA argmin GEMM geometry ----
#define GBM 128              // rows per block
#define GBN 256              // cols per block
#define GBK 64               // k per tile (8 tiles cover K=512)
#define NGROUPS 64           // 8192 / 128-col groups
#define MARGIN 3.0e-4f       // >= 2*eps(bf16 approx); R7-validated (absmax 0.0)

typedef __attribute__((ext_vector_type(8))) short short8v;   // 8 bf16 (4 VGPR)
typedef __attribute__((ext_vector_type(4))) float f32x4;     // MFMA C/D

// async global->LDS DMA, 16B/lane; LDS dest = wave-uniform base + lane*16 (linear)
#define GLD16(gp, lp)                                                          \
    __builtin_amdgcn_global_load_lds(                                          \
        (const __attribute__((address_space(1))) void*)(gp),                   \
        (__attribute__((address_space(3))) void*)(lp), 16, 0, 0)

__device__ __forceinline__ unsigned short f2bf(float f) {    // RTNE fp32->bf16
    unsigned u = __float_as_uint(f);
    u += 0x7FFFu + ((u >> 16) & 1u);
    return (unsigned short)(u >> 16);
}
__device__ __forceinline__ unsigned long long packwi(float w, int col) {
    // w > 0 always -> uint order == float order; low 32 bits = col ->
    // u64 min == (w, lowest col) lexicographic
    return ((unsigned long long)__float_as_uint(w) << 32) | (unsigned)col;
}
__device__ __forceinline__ float valof(unsigned long long p) {
    return __uint_as_float((unsigned)(p >> 32));
}

// ---------------- Kernel 1: row norms ||z_r||^2 (fp64 acc) + z -> bf16 conversion -----
__global__ __launch_bounds__(256) void z2_kernel(const float* __restrict__ z,
                                                 float* __restrict__ z2,
                                                 unsigned long long* __restrict__ zb8) {
    int row  = blockIdx.x * 4 + (threadIdx.x >> 6);
    int lane = threadIdx.x & 63;
    const float4* p = (const float4*)(z + (size_t)row * E_DIM);
    double s = 0.0;
#pragma unroll
    for (int it = 0; it < 2; ++it) {
        float4 v = p[lane + it * 64];
        s += (double)v.x * v.x + (double)v.y * v.y
           + (double)v.z * v.z + (double)v.w * v.w;
        unsigned long long pk =
              (unsigned long long)((unsigned)f2bf(v.x) | ((unsigned)f2bf(v.y) << 16))
            | ((unsigned long long)((unsigned)f2bf(v.z) | ((unsigned)f2bf(v.w) << 16)) << 32);
        zb8[(size_t)row * 128 + lane + it * 64] = pk;
    }
#pragma unroll
    for (int off = 32; off > 0; off >>= 1) s += __shfl_down(s, off);
    if (lane == 0) z2[row] = (float)s;
}

// ---------------- Kernel 1b: emb fp32 -> bf16 (RTNE), packed u64 stores ---------------
__global__ __launch_bounds__(256) void convb_kernel(const float* __restrict__ emb,
                                                    unsigned long long* __restrict__ embb8) {
    int t = blockIdx.x * 256 + threadIdx.x;     // 1,048,576 threads x 4 elems
    float4 v = ((const float4*)emb)[t];
    unsigned long long p =
          (unsigned long long)((unsigned)f2bf(v.x) | ((unsigned)f2bf(v.y) << 16))
        | ((unsigned long long)((unsigned)f2bf(v.z) | ((unsigned)f2bf(v.w) << 16)) << 32);
    embb8[t] = p;
}

// ---------------- Kernel 2: bf16 MFMA approx scores + per-128-col-group table ---------
// Approx w(r,n) = z2_r - 2*(bf16 z . bf16 e), fp32 MFMA accumulate. Per (row, group):
// packed u64 entry = w1_bits[63:32] | argmin_col[28:16] | delta_lb[15:0] (bf16-trunc
// (m2-m1), round-down -> conservative scan flag). R9/R10/R11-validated (absmax 0.0).
// R12: LDS-read-bandwidth attack. R11's 2x4 microtile cost 0.75 ds_read/MFMA -> 192 KB
// LDS read per block-tile (LDS-bound: MfmaUtil 23% at 47% occupancy). Revert to the
// 4x4 microtile (0.5 reads/MFMA, 128 KB/tile, 32 FLOP/LDS-byte ~= the balanced point)
// on 8 waves / 512 threads; global_load_lds staging keeps VGPR ~<60 so VGPR+64 AGPR
// <= 128 -> TWO blocks co-resident (launch_bounds(512,4)); the partner block's compute
// covers each block's per-tile DMA drain (single-buffered LDS, 2x48 KB < 160 KB).
__global__ __launch_bounds__(512, 4) void gemm_argmin_kernel(
        const unsigned short* __restrict__ zb,
        const unsigned short* __restrict__ embb,
        const float* __restrict__ z2s,
        unsigned long long* __restrict__ m1g) {
    __shared__ __align__(16) char smem[GBM * GBK * 2 + GBN * GBK * 2];  // 48 KB
    unsigned short* Al = (unsigned short*)smem;                   // 16 KB
    unsigned short* Bl = (unsigned short*)(smem + GBM * GBK * 2); // 32 KB
    __shared__ float z2sh[GBM];

    const int tid  = threadIdx.x;
    const int lane = tid & 63;
    const int wid  = tid >> 6;          // 0..7
    const int wr   = wid >> 2;          // 0..1: 64-row half
    const int wc   = wid & 3;           // 0..3: 64-col quarter
    const int bx   = blockIdx.x & 31;   // 32 n-blocks
    const int by   = blockIdx.x >> 5;   // 256 row-blocks
    const int row0 = by * GBM;
    const int nb0  = bx * GBN;

    if (tid < GBM) z2sh[tid] = z2s[row0 + tid];

    // ---- staging: per-lane swizzled global sources, linear LDS dests (2 A + 4 B /wave)
    const int lrow = lane >> 3;                        // lane's row within an 8-row chunk
    const int lswz = ((lane & 7) ^ lrow) * 8;          // swizzled k-granule (ushorts)
    // A: 16 chunks of 1KB, wave owns {2wid, 2wid+1}
    const unsigned short* srcA0 = zb + (size_t)(row0 + wid * 16 + lrow) * E_DIM + lswz;
    const unsigned short* srcA1 = srcA0 + 8 * E_DIM;
    unsigned short* dstA0 = Al + (wid * 2) * 512;
    unsigned short* dstA1 = dstA0 + 512;
    // B: 32 chunks of 1KB, wave owns {4wid .. 4wid+3}
    const unsigned short* srcB0 = embb + (size_t)(nb0 + wid * 32 + lrow) * E_DIM + lswz;
    const unsigned short* srcB1 = srcB0 + 8 * E_DIM;
    const unsigned short* srcB2 = srcB0 + 16 * E_DIM;
    const unsigned short* srcB3 = srcB0 + 24 * E_DIM;
    unsigned short* dstB0 = Bl + (wid * 4) * 512;
    unsigned short* dstB1 = dstB0 + 512;
    unsigned short* dstB2 = dstB0 + 1024;
    unsigned short* dstB3 = dstB0 + 1536;

    // ---- fragment read byte-offsets for kh=0; kh=1 is ^64 (granule+4 under the XOR)
    int aoff[4], boff[4];
#pragma unroll
    for (int ri = 0; ri < 4; ++ri) {
        int rowf = wr * 64 + ri * 16 + (lane & 15);
        aoff[ri] = rowf * 128 + (((lane >> 4) ^ (rowf & 7)) << 4);
    }
#pragma unroll
    for (int ci = 0; ci < 4; ++ci) {
        int rowf = wc * 64 + ci * 16 + (lane & 15);
        boff[ci] = rowf * 128 + (((lane >> 4) ^ (rowf & 7)) << 4);
    }

    f32x4 acc[4][4];
#pragma unroll
    for (int a = 0; a < 4; ++a)
#pragma unroll
        for (int b = 0; b < 4; ++b) acc[a][b] = (f32x4){0.f, 0.f, 0.f, 0.f};

#pragma unroll
    for (int kt = 0; kt < 8; ++kt) {
        // ---- stage tile kt: async DMA (latency covered by the co-resident block)
        GLD16(srcA0 + kt * GBK, dstA0);
        GLD16(srcA1 + kt * GBK, dstA1);
        GLD16(srcB0 + kt * GBK, dstB0);
        GLD16(srcB1 + kt * GBK, dstB1);
        GLD16(srcB2 + kt * GBK, dstB2);
        GLD16(srcB3 + kt * GBK, dstB3);
        __syncthreads();   // drains vmcnt: tile resident

        // ---- compute: 2 k-halves x 4x4 fragments = 32 MFMA (0.5 ds_read/MFMA)
#pragma unroll
        for (int kh = 0; kh < 2; ++kh) {
            short8v af[4], bfr[4];
#pragma unroll
            for (int ri = 0; ri < 4; ++ri)
                af[ri] = *(const short8v*)((const char*)Al + (aoff[ri] ^ (kh << 6)));
#pragma unroll
            for (int ci = 0; ci < 4; ++ci)
                bfr[ci] = *(const short8v*)((const char*)Bl + (boff[ci] ^ (kh << 6)));
#pragma unroll
            for (int ri = 0; ri < 4; ++ri)
#pragma unroll
                for (int ci = 0; ci < 4; ++ci)
                    acc[ri][ci] = __builtin_amdgcn_mfma_f32_16x16x32_bf16(
                        af[ri], bfr[ci], acc[ri][ci], 0, 0, 0);
        }
        __syncthreads();   // reads done -> next tile's DMA may overwrite
    }

    // ---- fold 1: per wave, (m1 packed, m2) over its 64 cols -> LDS (aliased on Al)
    unsigned long long* m1L = (unsigned long long*)smem;        // [128][4], 4 KB
    float*              m2L = (float*)(smem + 4096);            // [128][4], 2 KB
    const int colb = nb0 + wc * 64 + (lane & 15);
#pragma unroll
    for (int ri = 0; ri < 4; ++ri) {
#pragma unroll
        for (int i = 0; i < 4; ++i) {
            int row = wr * 64 + ri * 16 + ((lane >> 4) << 2) + i;
            float z2r = z2sh[row];
            float w0 = z2r - 2.f * acc[ri][0][i];
            float w1 = z2r - 2.f * acc[ri][1][i];
            float w2 = z2r - 2.f * acc[ri][2][i];
            float w3 = z2r - 2.f * acc[ri][3][i];
            unsigned long long m1 = packwi(w0, colb);
            float m2 = 3.4e38f;
            unsigned long long p;
            p = packwi(w1, colb + 16);
            if (p < m1) { m2 = valof(m1); m1 = p; } else m2 = fminf(m2, w1);
            p = packwi(w2, colb + 32);
            if (p < m1) { m2 = valof(m1); m1 = p; } else m2 = fminf(m2, w2);
            p = packwi(w3, colb + 48);
            if (p < m1) { m2 = valof(m1); m1 = p; } else m2 = fminf(m2, w3);
#pragma unroll
            for (int off = 1; off < 16; off <<= 1) {
                unsigned long long o1 = __shfl_xor(m1, off);
                float o2 = __shfl_xor(m2, off);
                float hi = fmaxf(valof(m1), valof(o1));
                m2 = fminf(fminf(m2, o2), hi);
                if (o1 < m1) m1 = o1;
            }
            if ((lane & 15) == ri * 4 + i) {
                m1L[row * 4 + wc] = m1;
                m2L[row * 4 + wc] = m2;
            }
        }
    }
    __syncthreads();

    // ---- fold 2: combine wave pairs (wc 0+1, 2+3) -> 128-col groups, pack, store
    if (tid < 256) {
        int row = tid >> 1, h = tid & 1;
        unsigned long long a = m1L[row * 4 + 2 * h];
        unsigned long long b = m1L[row * 4 + 2 * h + 1];
        float ma = m2L[row * 4 + 2 * h];
        float mb = m2L[row * 4 + 2 * h + 1];
        unsigned long long m1c = a < b ? a : b;
        float m2c = fminf(fminf(ma, mb), fmaxf(valof(a), valof(b)));
        float wv  = valof(m1c);
        unsigned col = (unsigned)(m1c & 0xFFFFu);               // global col < 8192
        unsigned dl  = __float_as_uint(m2c - wv) >> 16;         // bf16 trunc = round-down
        unsigned long long packed =
              ((unsigned long long)__float_as_uint(wv) << 32)
            | ((unsigned long long)col << 16) | dl;
        m1g[(size_t)(row0 + row) * NGROUPS + bx * 2 + h] = packed;
    }
}

// ---------------- Kernel 3: exact rescore of margin candidates -----------------------
// Reproduces the reference comparison EXACTLY: serial fp32 fma chain k=0..511 ascending,
// w = z2 - 2*acc (single rounding), ties -> lowest index.
__device__ __forceinline__ float exact_w(const float* zs, const float* __restrict__ emb,
                                         int col, float z2r) {
    const float* e = emb + (size_t)col * E_DIM;
    float acc = 0.f;
#pragma unroll 8
    for (int k = 0; k < E_DIM; ++k) acc = fmaf(zs[k], e[k], acc);
    return z2r - 2.f * acc;
}

__global__ __launch_bounds__(256) void rescore_kernel(
        const float* __restrict__ z, const float* __restrict__ emb,
        const float* __restrict__ z2s,
        const unsigned long long* __restrict__ m1g,
        float* __restrict__ idxf) {
    __shared__ __align__(16) float zsh[4][512];
    const int lane = threadIdx.x & 63;
    const int wid  = threadIdx.x >> 6;
    const int r    = blockIdx.x * 4 + wid;

    const float4* zr4 = (const float4*)(z + (size_t)r * E_DIM);
    ((float4*)zsh[wid])[lane]      = zr4[lane];
    ((float4*)zsh[wid])[lane + 64] = zr4[lane + 64];
    __syncthreads();
    const float* zs  = zsh[wid];
    const float  z2r = z2s[r];

    // one 128-col group per lane
    unsigned long long e = m1g[(size_t)r * NGROUPS + lane];
    float w1  = __uint_as_float((unsigned)(e >> 32));
    int   c1  = (int)((e >> 16) & 0xFFFFu);
    float dlb = __uint_as_float(((unsigned)e & 0xFFFFu) << 16);

    float gm = w1;
#pragma unroll
    for (int off = 1; off < 64; off <<= 1)
        gm = fminf(gm, __shfl_xor(gm, off));
    const float thr = gm + MARGIN;

    float wb = 3.4e38f; int ib = 0x7fffffff;
    if (w1 <= thr) {                             // group argmin candidate: single dot
        float w = exact_w(zs, emb, c1, z2r);
        if (w < wb || (w == wb && c1 < ib)) { wb = w; ib = c1; }
    }
    // full 128-col rescans for groups whose 2nd-min may be inside the margin
    unsigned long long mf = __ballot(w1 + dlb <= thr);
    while (mf) {
        int g = __ffsll((long long)mf) - 1; mf &= mf - 1;
        int col = g * 128 + lane;
        float w = exact_w(zs, emb, col, z2r);
        if (w < wb || (w == wb && col < ib)) { wb = w; ib = col; }
        col += 64;
        w = exact_w(zs, emb, col, z2r);
        if (w < wb || (w == wb && col < ib)) { wb = w; ib = col; }
    }
#pragma unroll
    for (int off = 1; off < 64; off <<= 1) {
        float wo = __shfl_xor(wb, off);
        int  io  = __shfl_xor(ib, off);
        if (wo < wb || (wo == wb && io < ib)) { wb = wo; ib = io; }
    }
    if (lane == 0) idxf[r] = (float)ib;
}

// ---------------- Kernel 4: gather + straight-through output + loss ----------------
__global__ __launch_bounds__(256) void output_kernel(const float* __restrict__ z,
                                                     const float* __restrict__ mask,
                                                     const float* __restrict__ emb,
                                                     const float* __restrict__ idxf,
                                                     float* __restrict__ out0,
                                                     float* __restrict__ loss) {
    const int nth = gridDim.x * blockDim.x;
    int t = blockIdx.x * blockDim.x + threadIdx.x;
    const float4* z4 = (const float4*)z;
    const float4* e4 = (const float4*)emb;
    float4* o4 = (float4*)out0;
    float partial = 0.f;
    for (int f = t; f < TOT_ELEMS / 4; f += nth) {
        int row = f >> 7;            // 128 float4 per 512-elem row
        int col = f & 127;
        int id  = (int)idxf[row];
        float m = mask[row];
        float4 zv = z4[f];
        float4 qv = e4[id * 128 + col];
        float dx = qv.x - zv.x, dy = qv.y - zv.y;
        float dz = qv.z - zv.z, dw = qv.w - zv.w;
        float4 ov;                   // z + (z_q - z): fp32 replication of ST estimator
        ov.x = zv.x + dx; ov.y = zv.y + dy;
        ov.z = zv.z + dz; ov.w = zv.w + dw;
        o4[f] = ov;
        partial += (dx * dx + dy * dy + dz * dz + dw * dw) * m;
    }
#pragma unroll
    for (int off = 32; off > 0; off >>= 1) partial += __shfl_down(partial, off);
    __shared__ float wsum[4];
    int lane = threadIdx.x & 63, w = threadIdx.x >> 6;
    if (lane == 0) wsum[w] = partial;
    __syncthreads();
    if (threadIdx.x == 0) {
        float s = wsum[0] + wsum[1] + wsum[2] + wsum[3];
        atomicAdd(loss, s * ((1.f + BETA) / (float)TOT_ELEMS));
    }
}

// ---------------- launcher -----------------------------------------------------------
// Scratch layout inside out0 (overwritten by output_kernel at the very end):
//   [0          .. 16,777,216)  m1g   u64[32768][64]    (packed group entries)
//   [16,777,216 .. 50,331,648)  zb    bf16[32768][512]
//   [50,331,648 .. 58,720,256)  embb  bf16[8192][512]
//   [58,720,256 .. 58,851,328)  z2    f32[32768]
extern "C" void kernel_launch(void* const* d_in, const int* in_sizes, int n_in,
                              void* d_out, int out_size, void* d_ws, size_t ws_size,
                              hipStream_t stream) {
    const float* z    = (const float*)d_in[0];   // (16,2048,512)
    const float* mask = (const float*)d_in[1];   // (16,2048)
    const float* emb  = (const float*)d_in[2];   // (8192,512)

    float* out0 = (float*)d_out;                 // z_q_st: 16777216 floats
    float* out1 = out0 + TOT_ELEMS;              // idx as float: 32768
    float* loss = out1 + NROWS;                  // scalar

    char* base = (char*)d_out;
    unsigned long long* m1g  = (unsigned long long*)base;
    unsigned short*     zb   = (unsigned short*)(base + 16777216);
    unsigned short*     embb = (unsigned short*)(base + 50331648);
    float*              z2st = (float*)(base + 58720256);

    hipMemsetAsync(loss, 0, sizeof(float), stream);
    z2_kernel<<<NROWS / 4, 256, 0, stream>>>(z, z2st, (unsigned long long*)zb);
    convb_kernel<<<4096, 256, 0, stream>>>(emb, (unsigned long long*)embb);
    gemm_argmin_kernel<<<(NROWS / GBM) * (N_E / GBN), 512, 0, stream>>>(
        zb, embb, z2st, m1g);
    rescore_kernel<<<NROWS / 4, 256, 0, stream>>>(z, emb, z2st, m1g, out1);
    output_kernel<<<4096, 256, 0, stream>>>(z, mask, emb, out1, out0, loss);
}